// Round 1
// baseline (213.775 us; speedup 1.0000x reference)
//
#include <hip/hip_runtime.h>

#define V 200000
#define R 100
#define D 128
#define K 20
#define B 128
#define N 50

// ---------------------------------------------------------------------------
// Kernel 0: rel_score[r] = relation_embedding[r] . W_att[2D:3D]
// ---------------------------------------------------------------------------
__global__ void k_rel_score(const float* __restrict__ RE,
                            const float* __restrict__ Watt,
                            float* __restrict__ rel_score) {
  __shared__ float red[128];
  const int r = blockIdx.x;
  const int t = threadIdx.x;
  red[t] = RE[r * D + t] * Watt[2 * D + t];
  __syncthreads();
  for (int s = 64; s > 0; s >>= 1) {
    if (t < s) red[t] += red[t + s];
    __syncthreads();
  }
  if (t == 0) rel_score[r] = red[0];
}

// ---------------------------------------------------------------------------
// Kernel 1: logits[(n*K+k)*B + b] = relu(ee.W0 + ne.W1 + rel_score[rid] + b_att)
// One wave (64 lanes) per (b,n) pair; each lane covers 2 of the 128 dims.
// ---------------------------------------------------------------------------
__global__ void k_logits(const int* __restrict__ eids,
                         const int* __restrict__ adjE,
                         const int* __restrict__ adjR,
                         const float* __restrict__ EE,
                         const float* __restrict__ Watt,
                         const float* __restrict__ batt,
                         const float* __restrict__ rel_score,
                         float* __restrict__ att) {
  const int bn = blockIdx.x;           // 0 .. B*N-1
  const int b = bn / N;
  const int n = bn % N;
  const int lane = threadIdx.x;        // 0 .. 63
  const int eid = eids[bn];

  // W_att slices, float2 per lane (d = 2*lane, 2*lane+1)
  const float2 wa_e = ((const float2*)Watt)[lane];          // W_att[0:128]
  const float2 wa_n = ((const float2*)(Watt + D))[lane];    // W_att[128:256]

  // ee . W0, wave reduction
  const float2 e2 = ((const float2*)(EE + (size_t)eid * D))[lane];
  float p = e2.x * wa_e.x + e2.y * wa_e.y;
  #pragma unroll
  for (int off = 32; off > 0; off >>= 1) p += __shfl_down(p, off);
  const float s_ee = __shfl(p, 0) + batt[0];   // broadcast to all lanes

  const int* ae = adjE + (size_t)eid * K;
  const int* ar = adjR + (size_t)eid * K;

  for (int k = 0; k < K; ++k) {
    const int nid = ae[k];
    const int rid = ar[k];
    const float2 ne2 = ((const float2*)(EE + (size_t)nid * D))[lane];
    float q = ne2.x * wa_n.x + ne2.y * wa_n.y;
    #pragma unroll
    for (int off = 32; off > 0; off >>= 1) q += __shfl_down(q, off);
    if (lane == 0) {
      float logit = s_ee + q + rel_score[rid];
      att[(n * K + k) * B + b] = logit > 0.0f ? logit : 0.0f;
    }
  }
}

// ---------------------------------------------------------------------------
// Kernel 2: softmax over the batch axis. One block of 128 threads per (n,k).
// ---------------------------------------------------------------------------
__global__ void k_softmax(float* __restrict__ att) {
  __shared__ float red[4];
  const int g = blockIdx.x;            // 0 .. N*K-1
  const int t = threadIdx.x;           // 0 .. 127  (= b)
  const float x = att[g * B + t];

  float m = x;
  #pragma unroll
  for (int off = 32; off > 0; off >>= 1) m = fmaxf(m, __shfl_down(m, off));
  if ((t & 63) == 0) red[t >> 6] = m;
  __syncthreads();
  const float mm = fmaxf(red[0], red[1]);

  const float e = __expf(x - mm);
  float s = e;
  #pragma unroll
  for (int off = 32; off > 0; off >>= 1) s += __shfl_down(s, off);
  if ((t & 63) == 0) red[2 + (t >> 6)] = s;
  __syncthreads();
  const float ss = red[2] + red[3];

  att[g * B + t] = e / ss;
}

// ---------------------------------------------------------------------------
// Kernel 3: neighbor_att + epilogue GEMV.
// G pairs per block, 128 threads (one per output dim d).
// ---------------------------------------------------------------------------
#define G 4
__global__ void k_out(const int* __restrict__ eids,
                      const int* __restrict__ adjE,
                      const float* __restrict__ EE,
                      const float* __restrict__ att,
                      const float* __restrict__ Wc,
                      const float* __restrict__ bc,
                      float* __restrict__ out) {
  __shared__ float agg[G][2 * D];
  __shared__ float s_att[G][K];
  __shared__ int   s_nid[G][K];

  const int d = threadIdx.x;           // 0 .. 127
  const int base = blockIdx.x * G;

  // stage neighbor ids + attention scalars
  for (int j = 0; j < G; ++j) {
    const int bn = base + j;
    const int b = bn / N;
    const int n = bn % N;
    const int eid = eids[bn];
    if (d < K) {
      s_nid[j][d] = adjE[(size_t)eid * K + d];
      s_att[j][d] = att[(n * K + d) * B + b];
    }
  }
  __syncthreads();

  // gather + weighted sum -> agg rows in LDS
  for (int j = 0; j < G; ++j) {
    const int bn = base + j;
    const int eid = eids[bn];
    const float ee = EE[(size_t)eid * D + d];
    float na = 0.0f;
    #pragma unroll
    for (int k = 0; k < K; ++k)
      na += s_att[j][k] * EE[(size_t)s_nid[j][k] * D + d];
    agg[j][d] = ee;
    agg[j][D + d] = na;
  }
  __syncthreads();

  // out[d] = relu(b_conv[d] + sum_i agg[i] * W_conv[i][d])
  float acc[G];
  #pragma unroll
  for (int j = 0; j < G; ++j) acc[j] = 0.0f;
  for (int i = 0; i < 2 * D; ++i) {
    const float w = Wc[i * D + d];     // coalesced; agg[j][i] is LDS broadcast
    #pragma unroll
    for (int j = 0; j < G; ++j) acc[j] += agg[j][i] * w;
  }
  const float bb = bc[d];
  for (int j = 0; j < G; ++j) {
    const float v = acc[j] + bb;
    out[(size_t)(base + j) * D + d] = v > 0.0f ? v : 0.0f;
  }
}

// ---------------------------------------------------------------------------
extern "C" void kernel_launch(void* const* d_in, const int* in_sizes, int n_in,
                              void* d_out, int out_size, void* d_ws, size_t ws_size,
                              hipStream_t stream) {
  const int*   eids = (const int*)d_in[0];      // [B*N]
  const int*   adjE = (const int*)d_in[1];      // [V*K]
  const int*   adjR = (const int*)d_in[2];      // [V*K]
  const float* EE   = (const float*)d_in[3];    // [V*D]
  const float* RE   = (const float*)d_in[4];    // [R*D]
  const float* Watt = (const float*)d_in[5];    // [3*D]
  const float* batt = (const float*)d_in[6];    // [1]
  const float* Wc   = (const float*)d_in[7];    // [2*D*D]
  const float* bc   = (const float*)d_in[8];    // [D]
  float* out = (float*)d_out;

  float* att       = (float*)d_ws;              // N*K*B floats (512 KB)
  float* rel_score = att + (size_t)N * K * B;   // R floats

  k_rel_score<<<R, 128, 0, stream>>>(RE, Watt, rel_score);
  k_logits<<<B * N, 64, 0, stream>>>(eids, adjE, adjR, EE, Watt, batt,
                                     rel_score, att);
  k_softmax<<<N * K, 128, 0, stream>>>(att);
  k_out<<<(B * N) / G, 128, 0, stream>>>(eids, adjE, EE, att, Wc, bc, out);
}

// Round 2
// 213.269 us; speedup vs baseline: 1.0024x; 1.0024x over previous
//
#include <hip/hip_runtime.h>

#define V 200000
#define R 100
#define D 128
#define K 20
#define B 128
#define N 50

// ---------------------------------------------------------------------------
// Kernel 1 (fused rel-score + logits):
//   att[(n*K+k)*B + b] = relu(ee.W0 + ne.W1 + nr.W2 + b_att)
// 256 threads = 4 waves; each wave owns one (b,n) pair.
// Within a wave: 4 groups of 16 lanes, each group handles one neighbor row
// per iteration (5 iterations cover K=20). Lane covers 8 dims (2x float4).
// ---------------------------------------------------------------------------
__global__ void k_logits(const int* __restrict__ eids,
                         const int* __restrict__ adjE,
                         const int* __restrict__ adjR,
                         const float* __restrict__ EE,
                         const float* __restrict__ RE,
                         const float* __restrict__ Watt,
                         const float* __restrict__ batt,
                         float* __restrict__ att) {
  const int lane = threadIdx.x & 63;
  const int wv   = threadIdx.x >> 6;
  const int bn   = blockIdx.x * 4 + wv;     // 0 .. B*N-1
  const int b = bn / N;
  const int n = bn % N;
  const int eid = eids[bn];

  // --- ee . W0 (full wave, float2/lane) ---
  const float2 wa_e = ((const float2*)Watt)[lane];
  const float2 e2   = ((const float2*)(EE + (size_t)eid * D))[lane];
  float p = e2.x * wa_e.x + e2.y * wa_e.y;
  #pragma unroll
  for (int off = 32; off > 0; off >>= 1) p += __shfl_down(p, off);
  const float s_ee = __shfl(p, 0) + batt[0];

  // --- neighbor dots: 16-lane groups ---
  const int g  = lane >> 4;                 // 0..3
  const int sl = lane & 15;                 // 0..15, covers dims 8*sl..8*sl+7
  const float4* wnp = (const float4*)(Watt + D + 8 * sl);
  const float4* wrp = (const float4*)(Watt + 2 * D + 8 * sl);
  const float4 wn0 = wnp[0], wn1 = wnp[1];
  const float4 wr0 = wrp[0], wr1 = wrp[1];

  const int* ae = adjE + eid * K;
  const int* ar = adjR + eid * K;

  float q[5];
  #pragma unroll
  for (int k5 = 0; k5 < 5; ++k5) {
    const int k = k5 * 4 + g;
    const int nid = ae[k];
    const int rid = ar[k];
    const float4* np = (const float4*)(EE + (size_t)nid * D + 8 * sl);
    const float4* rp = (const float4*)(RE + (size_t)rid * D + 8 * sl);
    const float4 n0 = np[0], n1 = np[1];
    const float4 r0 = rp[0], r1 = rp[1];
    float s = n0.x * wn0.x + n0.y * wn0.y + n0.z * wn0.z + n0.w * wn0.w
            + n1.x * wn1.x + n1.y * wn1.y + n1.z * wn1.z + n1.w * wn1.w
            + r0.x * wr0.x + r0.y * wr0.y + r0.z * wr0.z + r0.w * wr0.w
            + r1.x * wr1.x + r1.y * wr1.y + r1.z * wr1.z + r1.w * wr1.w;
    #pragma unroll
    for (int off = 8; off > 0; off >>= 1) s += __shfl_down(s, off, 16);
    q[k5] = s;
  }

  if (sl == 0) {
    #pragma unroll
    for (int k5 = 0; k5 < 5; ++k5) {
      const int k = k5 * 4 + g;
      const float logit = s_ee + q[k5];
      att[(n * K + k) * B + b] = logit > 0.0f ? logit : 0.0f;
    }
  }
}

// ---------------------------------------------------------------------------
// Kernel 2: softmax over the batch axis. One block of 128 threads per (n,k).
// ---------------------------------------------------------------------------
__global__ void k_softmax(float* __restrict__ att) {
  __shared__ float red[4];
  const int gg = blockIdx.x;           // 0 .. N*K-1
  const int t = threadIdx.x;           // 0 .. 127  (= b)
  const float x = att[gg * B + t];

  float m = x;
  #pragma unroll
  for (int off = 32; off > 0; off >>= 1) m = fmaxf(m, __shfl_down(m, off));
  if ((t & 63) == 0) red[t >> 6] = m;
  __syncthreads();
  const float mm = fmaxf(red[0], red[1]);

  const float e = __expf(x - mm);
  float s = e;
  #pragma unroll
  for (int off = 32; off > 0; off >>= 1) s += __shfl_down(s, off);
  if ((t & 63) == 0) red[2 + (t >> 6)] = s;
  __syncthreads();
  const float ss = red[2] + red[3];

  att[gg * B + t] = e / ss;
}

// ---------------------------------------------------------------------------
// Kernel 3: neighbor_att + epilogue GEMV.
// G=4 pairs per block, 256 threads = (d 0..127) x (h 0..1).
// Phase 2 splits the 2D-long inner product across h; float4 LDS reads.
// ---------------------------------------------------------------------------
#define G 4
__global__ void k_out(const int* __restrict__ eids,
                      const int* __restrict__ adjE,
                      const float* __restrict__ EE,
                      const float* __restrict__ att,
                      const float* __restrict__ Wc,
                      const float* __restrict__ bc,
                      float* __restrict__ out) {
  __shared__ float agg[G][2 * D];        // 4 KB
  __shared__ float part[2][G][D];        // 4 KB
  __shared__ float s_att[G][K];
  __shared__ int   s_nid[G][K];

  const int t = threadIdx.x;             // 0 .. 255
  const int d = t & 127;
  const int h = t >> 7;
  const int base = blockIdx.x * G;

  // stage neighbor ids + attention scalars (80 threads)
  if (t < G * K) {
    const int j = t / K, k = t % K;
    const int bn = base + j;
    const int b = bn / N;
    const int n = bn % N;
    const int eid = eids[bn];
    s_nid[j][k] = adjE[eid * K + k];
    s_att[j][k] = att[(n * K + k) * B + b];
  }
  __syncthreads();

  // phase 1: gather + weighted sum; thread-half h covers pairs {h, h+2}
  #pragma unroll
  for (int jj = 0; jj < 2; ++jj) {
    const int j = h + jj * 2;
    const int bn = base + j;
    const int eid = eids[bn];
    const float ee = EE[(size_t)eid * D + d];
    float na = 0.0f;
    #pragma unroll
    for (int k = 0; k < K; ++k)
      na += s_att[j][k] * EE[(size_t)s_nid[j][k] * D + d];
    agg[j][d] = ee;
    agg[j][D + d] = na;
  }
  __syncthreads();

  // phase 2: partial GEMV over i in [128h, 128h+128), all G pairs
  float acc0 = 0.f, acc1 = 0.f, acc2 = 0.f, acc3 = 0.f;
  const int ibase = h * D;
  #pragma unroll 4
  for (int c = 0; c < 32; ++c) {
    const int i = ibase + c * 4;
    const float4 a0 = *(const float4*)&agg[0][i];
    const float4 a1 = *(const float4*)&agg[1][i];
    const float4 a2 = *(const float4*)&agg[2][i];
    const float4 a3 = *(const float4*)&agg[3][i];
    const float w0 = Wc[(i + 0) * D + d];
    const float w1 = Wc[(i + 1) * D + d];
    const float w2 = Wc[(i + 2) * D + d];
    const float w3 = Wc[(i + 3) * D + d];
    acc0 += a0.x * w0 + a0.y * w1 + a0.z * w2 + a0.w * w3;
    acc1 += a1.x * w0 + a1.y * w1 + a1.z * w2 + a1.w * w3;
    acc2 += a2.x * w0 + a2.y * w1 + a2.z * w2 + a2.w * w3;
    acc3 += a3.x * w0 + a3.y * w1 + a3.z * w2 + a3.w * w3;
  }
  part[h][0][d] = acc0;
  part[h][1][d] = acc1;
  part[h][2][d] = acc2;
  part[h][3][d] = acc3;
  __syncthreads();

  // combine halves + bias + relu; thread-half h writes pairs {h, h+2}
  const float bb = bc[d];
  #pragma unroll
  for (int jj = 0; jj < 2; ++jj) {
    const int j = h + jj * 2;
    const float v = part[0][j][d] + part[1][j][d] + bb;
    out[(size_t)(base + j) * D + d] = v > 0.0f ? v : 0.0f;
  }
}

// ---------------------------------------------------------------------------
extern "C" void kernel_launch(void* const* d_in, const int* in_sizes, int n_in,
                              void* d_out, int out_size, void* d_ws, size_t ws_size,
                              hipStream_t stream) {
  const int*   eids = (const int*)d_in[0];      // [B*N]
  const int*   adjE = (const int*)d_in[1];      // [V*K]
  const int*   adjR = (const int*)d_in[2];      // [V*K]
  const float* EE   = (const float*)d_in[3];    // [V*D]
  const float* RE   = (const float*)d_in[4];    // [R*D]
  const float* Watt = (const float*)d_in[5];    // [3*D]
  const float* batt = (const float*)d_in[6];    // [1]
  const float* Wc   = (const float*)d_in[7];    // [2*D*D]
  const float* bc   = (const float*)d_in[8];    // [D]
  float* out = (float*)d_out;

  float* att = (float*)d_ws;                    // N*K*B floats (512 KB)

  k_logits<<<(B * N) / 4, 256, 0, stream>>>(eids, adjE, adjR, EE, RE, Watt,
                                            batt, att);
  k_softmax<<<N * K, 128, 0, stream>>>(att);
  k_out<<<(B * N) / G, 256, 0, stream>>>(eids, adjE, EE, att, Wc, bc, out);
}

// Round 3
// 207.779 us; speedup vs baseline: 1.0289x; 1.0264x over previous
//
#include <hip/hip_runtime.h>

#define V 200000
#define R 100
#define D 128
#define K 20
#define B 128
#define N 50

// ---------------------------------------------------------------------------
// Kernel 1 (fused rel-score + logits):
//   att[(n*K+k)*B + b] = relu(ee.W0 + ne.W1 + nr.W2 + b_att)
// 256 threads = 4 waves; each wave owns one (b,n) pair.
// 4 groups of 16 lanes per wave; each group handles one neighbor row per
// iteration (5 iterations cover K=20) -> all 20 row-gathers in flight.
// ---------------------------------------------------------------------------
__global__ void k_logits(const int* __restrict__ eids,
                         const int* __restrict__ adjE,
                         const int* __restrict__ adjR,
                         const float* __restrict__ EE,
                         const float* __restrict__ RE,
                         const float* __restrict__ Watt,
                         const float* __restrict__ batt,
                         float* __restrict__ att) {
  const int lane = threadIdx.x & 63;
  const int wv   = threadIdx.x >> 6;
  const int bn   = blockIdx.x * 4 + wv;     // 0 .. B*N-1
  const int b = bn / N;
  const int n = bn % N;
  const int eid = eids[bn];

  // --- ee . W0 (full wave, float2/lane) ---
  const float2 wa_e = ((const float2*)Watt)[lane];
  const float2 e2   = ((const float2*)(EE + (size_t)eid * D))[lane];
  float p = e2.x * wa_e.x + e2.y * wa_e.y;
  #pragma unroll
  for (int off = 32; off > 0; off >>= 1) p += __shfl_down(p, off);
  const float s_ee = __shfl(p, 0) + batt[0];

  // --- neighbor dots: 16-lane groups ---
  const int g  = lane >> 4;                 // 0..3
  const int sl = lane & 15;                 // 0..15, covers dims 8*sl..8*sl+7
  const float4* wnp = (const float4*)(Watt + D + 8 * sl);
  const float4* wrp = (const float4*)(Watt + 2 * D + 8 * sl);
  const float4 wn0 = wnp[0], wn1 = wnp[1];
  const float4 wr0 = wrp[0], wr1 = wrp[1];

  const int* ae = adjE + eid * K;
  const int* ar = adjR + eid * K;

  float q[5];
  #pragma unroll
  for (int k5 = 0; k5 < 5; ++k5) {
    const int k = k5 * 4 + g;
    const int nid = ae[k];
    const int rid = ar[k];
    const float4* np = (const float4*)(EE + (size_t)nid * D + 8 * sl);
    const float4* rp = (const float4*)(RE + (size_t)rid * D + 8 * sl);
    const float4 n0 = np[0], n1 = np[1];
    const float4 r0 = rp[0], r1 = rp[1];
    float s = n0.x * wn0.x + n0.y * wn0.y + n0.z * wn0.z + n0.w * wn0.w
            + n1.x * wn1.x + n1.y * wn1.y + n1.z * wn1.z + n1.w * wn1.w
            + r0.x * wr0.x + r0.y * wr0.y + r0.z * wr0.z + r0.w * wr0.w
            + r1.x * wr1.x + r1.y * wr1.y + r1.z * wr1.z + r1.w * wr1.w;
    #pragma unroll
    for (int off = 8; off > 0; off >>= 1) s += __shfl_down(s, off, 16);
    q[k5] = s;
  }

  if (sl == 0) {
    #pragma unroll
    for (int k5 = 0; k5 < 5; ++k5) {
      const int k = k5 * 4 + g;
      const float logit = s_ee + q[k5];
      att[(n * K + k) * B + b] = logit > 0.0f ? logit : 0.0f;
    }
  }
}

// ---------------------------------------------------------------------------
// Kernel 2: softmax over the batch axis. One block of 128 threads per (n,k).
// ---------------------------------------------------------------------------
__global__ void k_softmax(float* __restrict__ att) {
  __shared__ float red[4];
  const int gg = blockIdx.x;           // 0 .. N*K-1
  const int t = threadIdx.x;           // 0 .. 127  (= b)
  const float x = att[gg * B + t];

  float m = x;
  #pragma unroll
  for (int off = 32; off > 0; off >>= 1) m = fmaxf(m, __shfl_down(m, off));
  if ((t & 63) == 0) red[t >> 6] = m;
  __syncthreads();
  const float mm = fmaxf(red[0], red[1]);

  const float e = __expf(x - mm);
  float s = e;
  #pragma unroll
  for (int off = 32; off > 0; off >>= 1) s += __shfl_down(s, off);
  if ((t & 63) == 0) red[2 + (t >> 6)] = s;
  __syncthreads();
  const float ss = red[2] + red[3];

  att[gg * B + t] = e / ss;
}

// ---------------------------------------------------------------------------
// Kernel 3: neighbor_att + epilogue GEMV.
// G=8 pairs per block (halves W_conv L2 traffic vs G=4), 256 threads =
// (d 0..127) x (h 0..1). Phase 2 splits the 2D-long inner product across h.
// ---------------------------------------------------------------------------
#define G 8
__global__ void k_out(const int* __restrict__ eids,
                      const int* __restrict__ adjE,
                      const float* __restrict__ EE,
                      const float* __restrict__ att,
                      const float* __restrict__ Wc,
                      const float* __restrict__ bc,
                      float* __restrict__ out) {
  __shared__ float agg[G][2 * D];        // 8 KB
  __shared__ float part[2][G][D];        // 8 KB
  __shared__ float s_att[G][K];
  __shared__ int   s_nid[G][K];

  const int t = threadIdx.x;             // 0 .. 255
  const int d = t & 127;
  const int h = t >> 7;
  const int base = blockIdx.x * G;

  // stage neighbor ids + attention scalars (160 threads)
  if (t < G * K) {
    const int j = t / K, k = t % K;
    const int bn = base + j;
    const int b = bn / N;
    const int n = bn % N;
    const int eid = eids[bn];
    s_nid[j][k] = adjE[eid * K + k];
    s_att[j][k] = att[(n * K + k) * B + b];
  }
  __syncthreads();

  // phase 1: gather + weighted sum; half h covers pairs j = h, h+2, ...
  #pragma unroll
  for (int jj = 0; jj < G / 2; ++jj) {
    const int j = h + jj * 2;
    const int bn = base + j;
    const int eid = eids[bn];
    const float ee = EE[(size_t)eid * D + d];
    float na = 0.0f;
    #pragma unroll
    for (int k = 0; k < K; ++k)
      na += s_att[j][k] * EE[(size_t)s_nid[j][k] * D + d];
    agg[j][d] = ee;
    agg[j][D + d] = na;
  }
  __syncthreads();

  // phase 2: partial GEMV over i in [128h, 128h+128), all G pairs
  float acc[G];
  #pragma unroll
  for (int j = 0; j < G; ++j) acc[j] = 0.0f;
  const int ibase = h * D;
  for (int c = 0; c < 32; ++c) {
    const int i = ibase + c * 4;
    const float w0 = Wc[(i + 0) * D + d];
    const float w1 = Wc[(i + 1) * D + d];
    const float w2 = Wc[(i + 2) * D + d];
    const float w3 = Wc[(i + 3) * D + d];
    #pragma unroll
    for (int j = 0; j < G; ++j) {
      const float4 a = *(const float4*)&agg[j][i];   // same-address broadcast
      acc[j] += a.x * w0 + a.y * w1 + a.z * w2 + a.w * w3;
    }
  }
  #pragma unroll
  for (int j = 0; j < G; ++j) part[h][j][d] = acc[j];
  __syncthreads();

  // combine halves + bias + relu
  const float bb = bc[d];
  #pragma unroll
  for (int jj = 0; jj < G / 2; ++jj) {
    const int j = h + jj * 2;
    const float v = part[0][j][d] + part[1][j][d] + bb;
    out[(size_t)(base + j) * D + d] = v > 0.0f ? v : 0.0f;
  }
}

// ---------------------------------------------------------------------------
extern "C" void kernel_launch(void* const* d_in, const int* in_sizes, int n_in,
                              void* d_out, int out_size, void* d_ws, size_t ws_size,
                              hipStream_t stream) {
  const int*   eids = (const int*)d_in[0];      // [B*N]
  const int*   adjE = (const int*)d_in[1];      // [V*K]
  const int*   adjR = (const int*)d_in[2];      // [V*K]
  const float* EE   = (const float*)d_in[3];    // [V*D]
  const float* RE   = (const float*)d_in[4];    // [R*D]
  const float* Watt = (const float*)d_in[5];    // [3*D]
  const float* batt = (const float*)d_in[6];    // [1]
  const float* Wc   = (const float*)d_in[7];    // [2*D*D]
  const float* bc   = (const float*)d_in[8];    // [D]
  float* out = (float*)d_out;

  float* att = (float*)d_ws;                    // N*K*B floats (512 KB)

  k_logits<<<(B * N) / 4, 256, 0, stream>>>(eids, adjE, adjR, EE, RE, Watt,
                                            batt, att);
  k_softmax<<<N * K, 128, 0, stream>>>(att);
  k_out<<<(B * N) / G, 256, 0, stream>>>(eids, adjE, EE, att, Wc, bc, out);
}